// Round 2
// baseline (1693.108 us; speedup 1.0000x reference)
//
#include <hip/hip_runtime.h>
#include <hip/hip_bf16.h>
#include <math.h>

#define N_ATOMS 524288
#define DIM 256
#define NB 16384          // number of molecules / segments
#define M_STEPS 6

typedef short bf16x8 __attribute__((ext_vector_type(8)));
typedef float f32x16 __attribute__((ext_vector_type(16)));

__device__ __forceinline__ unsigned short f2bf(float f) {
    union { float f; unsigned u; } x; x.f = f;
    unsigned r = x.u + 0x7FFFu + ((x.u >> 16) & 1u);   // round-nearest-even
    return (unsigned short)(r >> 16);
}
__device__ __forceinline__ float bf2f(unsigned short s) {
    union { unsigned u; float f; } x; x.u = ((unsigned)s) << 16; return x.f;
}
// unpack a uint holding two bf16 (little-endian: e0 = low half, e1 = high half)
__device__ __forceinline__ float bflo(unsigned u) {
    union { unsigned u; float f; } x; x.u = u << 16; return x.f;
}
__device__ __forceinline__ float bfhi(unsigned u) {
    union { unsigned u; float f; } x; x.u = u & 0xFFFF0000u; return x.f;
}
__device__ __forceinline__ float sigmoidf_(float z) {
    return 1.0f / (1.0f + __expf(-z));
}
__device__ __forceinline__ float tanh_fast(float z) {
    return 1.0f - 2.0f / (__expf(2.0f * z) + 1.0f);
}

// ---------------------------------------------------------------------------
// Kernel 1: segment bounds via binary search (atom_split is sorted)
// ---------------------------------------------------------------------------
__global__ void bounds_kernel(const int* __restrict__ split, int* __restrict__ lb) {
    int b = blockIdx.x * blockDim.x + threadIdx.x;
    if (b > NB) return;
    int lo = 0, hi = N_ATOMS;
    while (lo < hi) {
        int mid = (lo + hi) >> 1;
        if (split[mid] < b) lo = mid + 1; else hi = mid;
    }
    lb[b] = lo;
}

// ---------------------------------------------------------------------------
// Kernel 2: pre-swizzle U into SPLIT bf16 (hi + residual-lo) B-fragment order
// for mfma_f32_32x32x16_bf16. hi+lo recovers U to ~2^-17 relative.
// ---------------------------------------------------------------------------
__global__ __launch_bounds__(256) void uswz_kernel(const float* __restrict__ U,
                                                   unsigned short* __restrict__ uhi,
                                                   unsigned short* __restrict__ ulo) {
    int d = blockIdx.x * 256 + threadIdx.x;
    int f = d >> 8;
    int r = d & 255;
    int jjp = r >> 6;
    int lane = r & 63;
    int nt = f >> 5, kc = f & 31;
    int n = nt * 32 + (lane & 31);
    int k = kc * 16 + (lane >> 5) * 8 + jjp * 2;
    float v0 = U[(size_t)k * 1024 + n];
    float v1 = U[(size_t)(k + 1) * 1024 + n];
    unsigned short h0 = f2bf(v0), h1 = f2bf(v1);
    unsigned short l0 = f2bf(v0 - bf2f(h0)), l1 = f2bf(v1 - bf2f(h1));
    ushort2 ph; ph.x = h0; ph.y = h1;
    ushort2 pl; pl.x = l0; pl.y = l1;
    const size_t o = (size_t)(f * 64 + lane) * 8 + jjp * 2;
    *(ushort2*)(&uhi[o]) = ph;
    *(ushort2*)(&ulo[o]) = pl;
}

// ---------------------------------------------------------------------------
// Kernel 3a: step-0 attention. h == 0 -> softmax uniform -> r = segment mean.
// Fused: stream fp32 x once, emit bf16 copy of x for later passes.
// Lane (g,q): g = atom subgroup (rows i+g), q = dim subgroup (16 dims).
// ---------------------------------------------------------------------------
__global__ __launch_bounds__(256) void attn0_cvt_kernel(
    const float* __restrict__ x,      // [N_ATOMS, DIM] fp32
    const int* __restrict__ lb,       // [NB+1]
    float* __restrict__ rout,         // [NB, DIM] (stride DIM)
    unsigned short* __restrict__ xb)  // [N_ATOMS, DIM] bf16 out
{
    const int t    = threadIdx.x;
    const int wave = t >> 6;
    const int lane = t & 63;
    const int b    = blockIdx.x * 4 + wave;
    const int g    = lane >> 4;
    const int q    = lane & 15;

    const int s = lb[b];
    const int e = lb[b + 1];

    float a0x=0.f,a0y=0.f,a0z=0.f,a0w=0.f;
    float a1x=0.f,a1y=0.f,a1z=0.f,a1w=0.f;
    float a2x=0.f,a2y=0.f,a2z=0.f,a2w=0.f;
    float a3x=0.f,a3y=0.f,a3z=0.f,a3w=0.f;
    float cnt = 0.f;

    for (int i = s + g; i < e; i += 4) {
        const float* xr = &x[(size_t)i * DIM + q * 16];
        const float4 c0 = *(const float4*)(xr + 0);
        const float4 c1 = *(const float4*)(xr + 4);
        const float4 c2 = *(const float4*)(xr + 8);
        const float4 c3 = *(const float4*)(xr + 12);
        cnt += 1.f;
        a0x += c0.x; a0y += c0.y; a0z += c0.z; a0w += c0.w;
        a1x += c1.x; a1y += c1.y; a1z += c1.z; a1w += c1.w;
        a2x += c2.x; a2y += c2.y; a2z += c2.z; a2w += c2.w;
        a3x += c3.x; a3y += c3.y; a3z += c3.z; a3w += c3.w;
        // bf16 copy: elements [16q .. 16q+16) of row i, packed 2/uint
        uint4 p0, p1;
        p0.x = (unsigned)f2bf(c0.x) | ((unsigned)f2bf(c0.y) << 16);
        p0.y = (unsigned)f2bf(c0.z) | ((unsigned)f2bf(c0.w) << 16);
        p0.z = (unsigned)f2bf(c1.x) | ((unsigned)f2bf(c1.y) << 16);
        p0.w = (unsigned)f2bf(c1.z) | ((unsigned)f2bf(c1.w) << 16);
        p1.x = (unsigned)f2bf(c2.x) | ((unsigned)f2bf(c2.y) << 16);
        p1.y = (unsigned)f2bf(c2.z) | ((unsigned)f2bf(c2.w) << 16);
        p1.z = (unsigned)f2bf(c3.x) | ((unsigned)f2bf(c3.y) << 16);
        p1.w = (unsigned)f2bf(c3.z) | ((unsigned)f2bf(c3.w) << 16);
        uint4* xw = (uint4*)(&xb[(size_t)i * DIM + q * 16]);
        xw[0] = p0;
        xw[1] = p1;
    }

#define XRED(v) { v += __shfl_xor(v, 16, 64); v += __shfl_xor(v, 32, 64); }
    XRED(a0x) XRED(a0y) XRED(a0z) XRED(a0w)
    XRED(a1x) XRED(a1y) XRED(a1z) XRED(a1w)
    XRED(a2x) XRED(a2y) XRED(a2z) XRED(a2w)
    XRED(a3x) XRED(a3y) XRED(a3z) XRED(a3w)
    XRED(cnt)
#undef XRED

    const float inv = (cnt > 0.f) ? (1.0f / cnt) : 0.f;
    float vx = (g==0) ? a0x : (g==1) ? a1x : (g==2) ? a2x : a3x;
    float vy = (g==0) ? a0y : (g==1) ? a1y : (g==2) ? a2y : a3y;
    float vz = (g==0) ? a0z : (g==1) ? a1z : (g==2) ? a2z : a3z;
    float vw = (g==0) ? a0w : (g==1) ? a1w : (g==2) ? a2w : a3w;
    float4 v; v.x = vx*inv; v.y = vy*inv; v.z = vz*inv; v.w = vw*inv;
    *(float4*)(&rout[(size_t)b * DIM + q * 16 + g * 4]) = v;
}

// ---------------------------------------------------------------------------
// Kernel 3b: fused segment attention over bf16 x. 4 atoms per wave per iter,
// one wave per segment, no LDS/barriers. Half the bytes of the fp32 version.
// ---------------------------------------------------------------------------
__global__ __launch_bounds__(256) void attn_bf16_kernel(
    const unsigned short* __restrict__ xb, // [N_ATOMS, DIM] bf16
    const int* __restrict__ lb,            // [NB+1]
    const float* __restrict__ h,           // [NB, DIM] fp32
    float* __restrict__ rout,              // output base
    int rstride)
{
    const int t    = threadIdx.x;
    const int wave = t >> 6;
    const int lane = t & 63;
    const int b    = blockIdx.x * 4 + wave;
    const int g    = lane >> 4;
    const int q    = lane & 15;

    const int s = lb[b];
    const int e = lb[b + 1];

    const float* hrow = &h[(size_t)b * DIM + q * 16];
    const float4 hv0 = *(const float4*)(hrow + 0);
    const float4 hv1 = *(const float4*)(hrow + 4);
    const float4 hv2 = *(const float4*)(hrow + 8);
    const float4 hv3 = *(const float4*)(hrow + 12);

    float a0x=0.f,a0y=0.f,a0z=0.f,a0w=0.f;
    float a1x=0.f,a1y=0.f,a1z=0.f,a1w=0.f;
    float a2x=0.f,a2y=0.f,a2z=0.f,a2w=0.f;
    float a3x=0.f,a3y=0.f,a3z=0.f,a3w=0.f;
    float ssum = 0.f;

    int i = s + g;
    uint4 A = {0,0,0,0}, B = {0,0,0,0};
    if (i < e) {
        const uint4* xr = (const uint4*)(&xb[(size_t)i * DIM + q * 16]);
        A = xr[0]; B = xr[1];
    }
    while (i < e) {
        // 1-deep software pipeline: issue next-iter loads first (clamped addr)
        const int inext = i + 4;
        const int iload = (inext < e) ? inext : i;
        const uint4* xr = (const uint4*)(&xb[(size_t)iload * DIM + q * 16]);
        const uint4 nA = xr[0];
        const uint4 nB = xr[1];

        const float4 c0 = {bflo(A.x), bfhi(A.x), bflo(A.y), bfhi(A.y)};
        const float4 c1 = {bflo(A.z), bfhi(A.z), bflo(A.w), bfhi(A.w)};
        const float4 c2 = {bflo(B.x), bfhi(B.x), bflo(B.y), bfhi(B.y)};
        const float4 c3 = {bflo(B.z), bfhi(B.z), bflo(B.w), bfhi(B.w)};

        float d01 = c0.x*hv0.x + c0.y*hv0.y + c0.z*hv0.z + c0.w*hv0.w
                  + c1.x*hv1.x + c1.y*hv1.y + c1.z*hv1.z + c1.w*hv1.w;
        float d23 = c2.x*hv2.x + c2.y*hv2.y + c2.z*hv2.z + c2.w*hv2.w
                  + c3.x*hv3.x + c3.y*hv3.y + c3.z*hv3.z + c3.w*hv3.w;
        float d = d01 + d23;
        d += __shfl_xor(d, 1, 64);
        d += __shfl_xor(d, 2, 64);
        d += __shfl_xor(d, 4, 64);
        d += __shfl_xor(d, 8, 64);
        const float ee = __expf(d);
        ssum += ee;
        a0x += ee*c0.x; a0y += ee*c0.y; a0z += ee*c0.z; a0w += ee*c0.w;
        a1x += ee*c1.x; a1y += ee*c1.y; a1z += ee*c1.z; a1w += ee*c1.w;
        a2x += ee*c2.x; a2y += ee*c2.y; a2z += ee*c2.z; a2w += ee*c2.w;
        a3x += ee*c3.x; a3y += ee*c3.y; a3z += ee*c3.z; a3w += ee*c3.w;

        A = nA; B = nB;
        i = inext;
    }

#define XRED(v) { v += __shfl_xor(v, 16, 64); v += __shfl_xor(v, 32, 64); }
    XRED(a0x) XRED(a0y) XRED(a0z) XRED(a0w)
    XRED(a1x) XRED(a1y) XRED(a1z) XRED(a1w)
    XRED(a2x) XRED(a2y) XRED(a2z) XRED(a2w)
    XRED(a3x) XRED(a3y) XRED(a3z) XRED(a3w)
    XRED(ssum)
#undef XRED

    const float inv = (ssum > 0.f) ? (1.0f / ssum) : 0.f;
    float vx = (g==0) ? a0x : (g==1) ? a1x : (g==2) ? a2x : a3x;
    float vy = (g==0) ? a0y : (g==1) ? a1y : (g==2) ? a2y : a3y;
    float vz = (g==0) ? a0z : (g==1) ? a1z : (g==2) ? a2z : a3z;
    float vw = (g==0) ? a0w : (g==1) ? a1w : (g==2) ? a2w : a3w;
    float4 v; v.x = vx*inv; v.y = vy*inv; v.z = vz*inv; v.w = vw*inv;
    *(float4*)(&rout[(size_t)b * rstride + q * 16 + g * 4]) = v;
}

// ---------------------------------------------------------------------------
// Kernel 4: fused LSTM step via SPLIT-bf16 MFMA (3-term: AhUh + AhUl + AlUh),
// gemm rel-error ~2^-16. kb0=4 skips the h-half when h==0 (step 0).
// ---------------------------------------------------------------------------
#define LBM 128
#define LBK 64
#define APAD 8
__global__ __launch_bounds__(256, 2) void lstm_mfma_kernel(
    const float* __restrict__ h_in,
    const float* __restrict__ r,
    const unsigned short* __restrict__ uhi,
    const unsigned short* __restrict__ ulo,
    const float* __restrict__ bias,
    float* __restrict__ c,
    float* __restrict__ h_out,
    float* __restrict__ hdup,         // if non-null: also write h, row stride 512
    int kb0)
{
    __shared__ unsigned short Ah[LBM][LBK + APAD];
    __shared__ unsigned short Al[LBM][LBK + APAD];

    const int t = threadIdx.x;
    const int w = t >> 6;
    const int lane = t & 63;
    const int m0 = blockIdx.y * LBM;
    const int bx = blockIdx.x;

    f32x16 acc[8];
    #pragma unroll
    for (int et = 0; et < 8; ++et)
        #pragma unroll
        for (int q = 0; q < 16; ++q) acc[et][q] = 0.0f;

    for (int kb = kb0; kb < 8; ++kb) {
        const float* A = (kb < 4) ? h_in : r;
        const int ak = (kb & 3) * LBK;
        __syncthreads();
        #pragma unroll
        for (int i = 0; i < 8; ++i) {
            int idx = i * 256 + t;
            int row = idx >> 4, k4 = idx & 15;
            float4 v = *(const float4*)(&A[(size_t)(m0 + row) * DIM + ak + k4 * 4]);
            ushort4 bh, bl;
            bh.x = f2bf(v.x); bl.x = f2bf(v.x - bf2f(bh.x));
            bh.y = f2bf(v.y); bl.y = f2bf(v.y - bf2f(bh.y));
            bh.z = f2bf(v.z); bl.z = f2bf(v.z - bf2f(bh.z));
            bh.w = f2bf(v.w); bl.w = f2bf(v.w - bf2f(bh.w));
            *(ushort4*)(&Ah[row][k4 * 4]) = bh;
            *(ushort4*)(&Al[row][k4 * 4]) = bl;
        }
        __syncthreads();
        #pragma unroll
        for (int kc = 0; kc < 4; ++kc) {
            bf16x8 afh = *(const bf16x8*)(&Ah[w * 32 + (lane & 31)][kc * 16 + (lane >> 5) * 8]);
            bf16x8 afl = *(const bf16x8*)(&Al[w * 32 + (lane & 31)][kc * 16 + (lane >> 5) * 8]);
            const int kglob = kb * 4 + kc;
            #pragma unroll
            for (int et = 0; et < 8; ++et) {
                const int g = et >> 1;
                const int nt = g * 8 + bx * 2 + (et & 1);
                const size_t fo = ((size_t)(nt * 32 + kglob) * 64 + lane) * 8;
                bf16x8 bh = *(const bf16x8*)(&uhi[fo]);
                bf16x8 bl = *(const bf16x8*)(&ulo[fo]);
                acc[et] = __builtin_amdgcn_mfma_f32_32x32x16_bf16(afh, bh, acc[et], 0, 0, 0);
                acc[et] = __builtin_amdgcn_mfma_f32_32x32x16_bf16(afh, bl, acc[et], 0, 0, 0);
                acc[et] = __builtin_amdgcn_mfma_f32_32x32x16_bf16(afl, bh, acc[et], 0, 0, 0);
            }
        }
    }

    const int col32 = lane & 31;
    const int rbase = m0 + w * 32 + 4 * (lane >> 5);
    #pragma unroll
    for (int jh = 0; jh < 2; ++jh) {
        const int col = bx * 64 + jh * 32 + col32;
        const float bi = bias[col];
        const float bf_ = bias[256 + col];
        const float bo = bias[512 + col];
        const float bg = bias[768 + col];
        const f32x16 zi = acc[0 * 2 + jh];
        const f32x16 zf = acc[1 * 2 + jh];
        const f32x16 zo = acc[2 * 2 + jh];
        const f32x16 zg = acc[3 * 2 + jh];
        #pragma unroll
        for (int reg = 0; reg < 16; ++reg) {
            const int row = rbase + (reg & 3) + 8 * (reg >> 2);
            const size_t idx = (size_t)row * DIM + col;
            const float ig = sigmoidf_(zi[reg] + bi);
            const float fg = sigmoidf_(zf[reg] + bf_);
            const float og = sigmoidf_(zo[reg] + bo);
            const float gg = tanh_fast(zg[reg] + bg);
            const float cn = fg * c[idx] + ig * gg;
            c[idx] = cn;
            const float hn = og * tanh_fast(cn);
            h_out[idx] = hn;
            if (hdup) hdup[(size_t)row * 512 + col] = hn;
        }
    }
}

// ---------------------------------------------------------------------------
extern "C" void kernel_launch(void* const* d_in, const int* in_sizes, int n_in,
                              void* d_out, int out_size, void* d_ws, size_t ws_size,
                              hipStream_t stream) {
    const float* x     = (const float*)d_in[0];
    const int*   split = (const int*)d_in[1];
    const float* U     = (const float*)d_in[2];
    const float* bias  = (const float*)d_in[3];
    float* out = (float*)d_out;

    char* ws = (char*)d_ws;
    const size_t lb_bytes  = ((size_t)(NB + 1) * sizeof(int) + 255) & ~(size_t)255;
    const size_t mat_bytes = (size_t)NB * DIM * sizeof(float);   // 16 MB
    int*   lb   = (int*)ws;
    float* hA   = (float*)(ws + lb_bytes);
    float* hB   = (float*)(ws + lb_bytes + mat_bytes);
    float* cbuf = (float*)(ws + lb_bytes + 2 * mat_bytes);
    float* rbuf = (float*)(ws + lb_bytes + 3 * mat_bytes);
    unsigned short* uhi = (unsigned short*)(ws + lb_bytes + 4 * mat_bytes);          // 1 MB
    unsigned short* ulo = (unsigned short*)(ws + lb_bytes + 4 * mat_bytes + (1<<20)); // 1 MB
    unsigned short* xb  = (unsigned short*)(ws + lb_bytes + 4 * mat_bytes + (2<<20)); // 256 MB

    bounds_kernel<<<(NB + 1 + 255) / 256, 256, 0, stream>>>(split, lb);
    uswz_kernel<<<1024, 256, 0, stream>>>(U, uhi, ulo);
    hipMemsetAsync(cbuf, 0, mat_bytes, stream);

    float* h_cur = hA;
    float* h_nxt = hB;
    for (int m = 0; m < M_STEPS; ++m) {
        const bool last = (m == M_STEPS - 1);
        float* rdst   = last ? (out + DIM) : rbuf;
        int    rstrid = last ? (2 * DIM) : DIM;
        if (m == 0) {
            // h == 0: r = segment mean; also emits bf16 x for later passes
            attn0_cvt_kernel<<<NB / 4, 256, 0, stream>>>(x, lb, rbuf, xb);
        } else {
            attn_bf16_kernel<<<NB / 4, 256, 0, stream>>>(xb, lb, h_cur, rdst, rstrid);
        }
        if (!last) {
            dim3 grid(4, NB / LBM);
            float* hdup = (m == M_STEPS - 2) ? out : (float*)nullptr;
            // m==0: h half of K is all-zero -> kb0=4 skips it (h_in unused)
            lstm_mfma_kernel<<<grid, 256, 0, stream>>>(
                (m == 0) ? rbuf : h_cur, rbuf, uhi, ulo, bias, cbuf, h_nxt, hdup,
                (m == 0) ? 4 : 0);
            float* tmp = h_cur; h_cur = h_nxt; h_nxt = tmp;
        }
    }
}

// Round 3
// 1275.391 us; speedup vs baseline: 1.3275x; 1.3275x over previous
//
#include <hip/hip_runtime.h>
#include <hip/hip_bf16.h>
#include <math.h>

#define N_ATOMS 524288
#define DIM 256
#define NB 16384          // number of molecules / segments
#define M_STEPS 6

typedef _Float16 f16x8 __attribute__((ext_vector_type(8)));
typedef float f32x16 __attribute__((ext_vector_type(16)));

__device__ __forceinline__ float sigmoidf_(float z) {
    return 1.0f / (1.0f + __expf(-z));
}
__device__ __forceinline__ float tanh_fast(float z) {
    return 1.0f - 2.0f / (__expf(2.0f * z) + 1.0f);
}
// unpack a uint holding two fp16
__device__ __forceinline__ float2 h2f2(unsigned u) {
    union { unsigned u; _Float16 h[2]; } x; x.u = u;
    float2 r; r.x = (float)x.h[0]; r.y = (float)x.h[1]; return r;
}

// ---------------------------------------------------------------------------
// Kernel 1: segment bounds via binary search (atom_split is sorted)
// ---------------------------------------------------------------------------
__global__ void bounds_kernel(const int* __restrict__ split, int* __restrict__ lb) {
    int b = blockIdx.x * blockDim.x + threadIdx.x;
    if (b > NB) return;
    int lo = 0, hi = N_ATOMS;
    while (lo < hi) {
        int mid = (lo + hi) >> 1;
        if (split[mid] < b) lo = mid + 1; else hi = mid;
    }
    lb[b] = lo;
}

// ---------------------------------------------------------------------------
// Kernel 2: pre-swizzle U (f32 [512,1024]) into fp16 B-fragment order for
// mfma_f32_32x32x16_f16. Frag f = nt*32 + kglob; lane l holds
// B[k = kglob*16 + (l>>5)*8 + jj][n = nt*32 + (l&31)], jj=0..7. 1 MB total.
// ---------------------------------------------------------------------------
__global__ __launch_bounds__(256) void uswz_kernel(const float* __restrict__ U,
                                                   _Float16* __restrict__ uh) {
    int d = blockIdx.x * 256 + threadIdx.x;
    int f = d >> 8;
    int r = d & 255;
    int jjp = r >> 6;
    int lane = r & 63;
    int nt = f >> 5, kc = f & 31;
    int n = nt * 32 + (lane & 31);
    int k = kc * 16 + (lane >> 5) * 8 + jjp * 2;
    union { unsigned u; _Float16 h[2]; } p;
    p.h[0] = (_Float16)U[(size_t)k * 1024 + n];
    p.h[1] = (_Float16)U[(size_t)(k + 1) * 1024 + n];
    *(unsigned*)(&uh[(size_t)(f * 64 + lane) * 8 + jjp * 2]) = p.u;
}

// ---------------------------------------------------------------------------
// Kernel 3a: step-0 attention. h == 0 -> softmax uniform -> r = segment mean.
// Fused: stream fp32 x once, emit fp16 copy of x for later passes.
// ---------------------------------------------------------------------------
__global__ __launch_bounds__(256) void attn0_cvt_kernel(
    const float* __restrict__ x,      // [N_ATOMS, DIM] fp32
    const int* __restrict__ lb,       // [NB+1]
    float* __restrict__ rout,         // [NB, DIM] (stride DIM)
    _Float16* __restrict__ xh)        // [N_ATOMS, DIM] fp16 out
{
    const int t    = threadIdx.x;
    const int wave = t >> 6;
    const int lane = t & 63;
    const int b    = blockIdx.x * 4 + wave;
    const int g    = lane >> 4;
    const int q    = lane & 15;

    const int s = lb[b];
    const int e = lb[b + 1];

    float a0x=0.f,a0y=0.f,a0z=0.f,a0w=0.f;
    float a1x=0.f,a1y=0.f,a1z=0.f,a1w=0.f;
    float a2x=0.f,a2y=0.f,a2z=0.f,a2w=0.f;
    float a3x=0.f,a3y=0.f,a3z=0.f,a3w=0.f;
    float cnt = 0.f;

    for (int i = s + g; i < e; i += 4) {
        const float* xr = &x[(size_t)i * DIM + q * 16];
        const float4 c0 = *(const float4*)(xr + 0);
        const float4 c1 = *(const float4*)(xr + 4);
        const float4 c2 = *(const float4*)(xr + 8);
        const float4 c3 = *(const float4*)(xr + 12);
        cnt += 1.f;
        a0x += c0.x; a0y += c0.y; a0z += c0.z; a0w += c0.w;
        a1x += c1.x; a1y += c1.y; a1z += c1.z; a1w += c1.w;
        a2x += c2.x; a2y += c2.y; a2z += c2.z; a2w += c2.w;
        a3x += c3.x; a3y += c3.y; a3z += c3.z; a3w += c3.w;
        union { _Float16 h[16]; uint4 v[2]; } P;
        P.h[0]=(_Float16)c0.x; P.h[1]=(_Float16)c0.y; P.h[2]=(_Float16)c0.z; P.h[3]=(_Float16)c0.w;
        P.h[4]=(_Float16)c1.x; P.h[5]=(_Float16)c1.y; P.h[6]=(_Float16)c1.z; P.h[7]=(_Float16)c1.w;
        P.h[8]=(_Float16)c2.x; P.h[9]=(_Float16)c2.y; P.h[10]=(_Float16)c2.z; P.h[11]=(_Float16)c2.w;
        P.h[12]=(_Float16)c3.x; P.h[13]=(_Float16)c3.y; P.h[14]=(_Float16)c3.z; P.h[15]=(_Float16)c3.w;
        uint4* xw = (uint4*)(&xh[(size_t)i * DIM + q * 16]);
        xw[0] = P.v[0];
        xw[1] = P.v[1];
    }

#define XRED(v) { v += __shfl_xor(v, 16, 64); v += __shfl_xor(v, 32, 64); }
    XRED(a0x) XRED(a0y) XRED(a0z) XRED(a0w)
    XRED(a1x) XRED(a1y) XRED(a1z) XRED(a1w)
    XRED(a2x) XRED(a2y) XRED(a2z) XRED(a2w)
    XRED(a3x) XRED(a3y) XRED(a3z) XRED(a3w)
    XRED(cnt)
#undef XRED

    const float inv = (cnt > 0.f) ? (1.0f / cnt) : 0.f;
    float vx = (g==0) ? a0x : (g==1) ? a1x : (g==2) ? a2x : a3x;
    float vy = (g==0) ? a0y : (g==1) ? a1y : (g==2) ? a2y : a3y;
    float vz = (g==0) ? a0z : (g==1) ? a1z : (g==2) ? a2z : a3z;
    float vw = (g==0) ? a0w : (g==1) ? a1w : (g==2) ? a2w : a3w;
    float4 v; v.x = vx*inv; v.y = vy*inv; v.z = vz*inv; v.w = vw*inv;
    *(float4*)(&rout[(size_t)b * DIM + q * 16 + g * 4]) = v;
}

// ---------------------------------------------------------------------------
// Kernel 3b: fused segment attention over fp16 x. 4 atoms per wave per iter,
// one wave per segment, no LDS/barriers.
// ---------------------------------------------------------------------------
__global__ __launch_bounds__(256) void attn_f16_kernel(
    const _Float16* __restrict__ xhp,  // [N_ATOMS, DIM] fp16
    const int* __restrict__ lb,        // [NB+1]
    const float* __restrict__ h,       // [NB, DIM] fp32
    float* __restrict__ rout,          // output base
    int rstride)
{
    const int t    = threadIdx.x;
    const int wave = t >> 6;
    const int lane = t & 63;
    const int b    = blockIdx.x * 4 + wave;
    const int g    = lane >> 4;
    const int q    = lane & 15;

    const int s = lb[b];
    const int e = lb[b + 1];

    const float* hrow = &h[(size_t)b * DIM + q * 16];
    const float4 hv0 = *(const float4*)(hrow + 0);
    const float4 hv1 = *(const float4*)(hrow + 4);
    const float4 hv2 = *(const float4*)(hrow + 8);
    const float4 hv3 = *(const float4*)(hrow + 12);

    float a0x=0.f,a0y=0.f,a0z=0.f,a0w=0.f;
    float a1x=0.f,a1y=0.f,a1z=0.f,a1w=0.f;
    float a2x=0.f,a2y=0.f,a2z=0.f,a2w=0.f;
    float a3x=0.f,a3y=0.f,a3z=0.f,a3w=0.f;
    float ssum = 0.f;

    int i = s + g;
    uint4 A = {0,0,0,0}, B = {0,0,0,0};
    if (i < e) {
        const uint4* xr = (const uint4*)(&xhp[(size_t)i * DIM + q * 16]);
        A = xr[0]; B = xr[1];
    }
    while (i < e) {
        const int inext = i + 4;
        const int iload = (inext < e) ? inext : i;
        const uint4* xr = (const uint4*)(&xhp[(size_t)iload * DIM + q * 16]);
        const uint4 nA = xr[0];
        const uint4 nB = xr[1];

        const float2 p0 = h2f2(A.x), p1 = h2f2(A.y), p2 = h2f2(A.z), p3 = h2f2(A.w);
        const float2 p4 = h2f2(B.x), p5 = h2f2(B.y), p6 = h2f2(B.z), p7 = h2f2(B.w);
        const float4 c0 = {p0.x, p0.y, p1.x, p1.y};
        const float4 c1 = {p2.x, p2.y, p3.x, p3.y};
        const float4 c2 = {p4.x, p4.y, p5.x, p5.y};
        const float4 c3 = {p6.x, p6.y, p7.x, p7.y};

        float d01 = c0.x*hv0.x + c0.y*hv0.y + c0.z*hv0.z + c0.w*hv0.w
                  + c1.x*hv1.x + c1.y*hv1.y + c1.z*hv1.z + c1.w*hv1.w;
        float d23 = c2.x*hv2.x + c2.y*hv2.y + c2.z*hv2.z + c2.w*hv2.w
                  + c3.x*hv3.x + c3.y*hv3.y + c3.z*hv3.z + c3.w*hv3.w;
        float d = d01 + d23;
        d += __shfl_xor(d, 1, 64);
        d += __shfl_xor(d, 2, 64);
        d += __shfl_xor(d, 4, 64);
        d += __shfl_xor(d, 8, 64);
        const float ee = __expf(d);
        ssum += ee;
        a0x += ee*c0.x; a0y += ee*c0.y; a0z += ee*c0.z; a0w += ee*c0.w;
        a1x += ee*c1.x; a1y += ee*c1.y; a1z += ee*c1.z; a1w += ee*c1.w;
        a2x += ee*c2.x; a2y += ee*c2.y; a2z += ee*c2.z; a2w += ee*c2.w;
        a3x += ee*c3.x; a3y += ee*c3.y; a3z += ee*c3.z; a3w += ee*c3.w;

        A = nA; B = nB;
        i = inext;
    }

#define XRED(v) { v += __shfl_xor(v, 16, 64); v += __shfl_xor(v, 32, 64); }
    XRED(a0x) XRED(a0y) XRED(a0z) XRED(a0w)
    XRED(a1x) XRED(a1y) XRED(a1z) XRED(a1w)
    XRED(a2x) XRED(a2y) XRED(a2z) XRED(a2w)
    XRED(a3x) XRED(a3y) XRED(a3z) XRED(a3w)
    XRED(ssum)
#undef XRED

    const float inv = (ssum > 0.f) ? (1.0f / ssum) : 0.f;
    float vx = (g==0) ? a0x : (g==1) ? a1x : (g==2) ? a2x : a3x;
    float vy = (g==0) ? a0y : (g==1) ? a1y : (g==2) ? a2y : a3y;
    float vz = (g==0) ? a0z : (g==1) ? a1z : (g==2) ? a2z : a3z;
    float vw = (g==0) ? a0w : (g==1) ? a1w : (g==2) ? a2w : a3w;
    float4 v; v.x = vx*inv; v.y = vy*inv; v.z = vz*inv; v.w = vw*inv;
    *(float4*)(&rout[(size_t)b * rstride + q * 16 + g * 4]) = v;
}

// ---------------------------------------------------------------------------
// Kernel 4: fused LSTM step via fp16 MFMA (single term, ~2^-11 rel error).
// B (U) fragments for the block's 8 nt-tiles are staged in LDS once per kb
// and shared by all 4 waves (cuts U L2 traffic 4x vs per-wave streaming).
// kb0=4 skips the h-half when h==0 (step 0).
// ---------------------------------------------------------------------------
#define LBM 128
#define LBK 64
#define APAD 8
__global__ __launch_bounds__(256, 2) void lstm_mfma_kernel(
    const float* __restrict__ h_in,
    const float* __restrict__ r,
    const _Float16* __restrict__ uh,
    const float* __restrict__ bias,
    float* __restrict__ c,
    float* __restrict__ h_out,
    float* __restrict__ hdup,         // if non-null: also write h, row stride 512
    int kb0)
{
    __shared__ _Float16 As[LBM][LBK + APAD];
    __shared__ _Float16 Bs[8 * 4 * 512];   // [run][kc][lane*8] = 32 KB

    const int t = threadIdx.x;
    const int w = t >> 6;
    const int lane = t & 63;
    const int m0 = blockIdx.y * LBM;
    const int bx = blockIdx.x;

    f32x16 acc[8];
    #pragma unroll
    for (int et = 0; et < 8; ++et)
        #pragma unroll
        for (int q = 0; q < 16; ++q) acc[et][q] = 0.0f;

    for (int kb = kb0; kb < 8; ++kb) {
        const float* A = (kb < 4) ? h_in : r;
        const int ak = (kb & 3) * LBK;
        __syncthreads();
        // stage A tile (fp32 -> fp16)
        #pragma unroll
        for (int i = 0; i < 8; ++i) {
            int idx = i * 256 + t;
            int row = idx >> 4, k4 = idx & 15;
            float4 v = *(const float4*)(&A[(size_t)(m0 + row) * DIM + ak + k4 * 4]);
            union { _Float16 h[4]; ushort4 u; } bh;
            bh.h[0] = (_Float16)v.x; bh.h[1] = (_Float16)v.y;
            bh.h[2] = (_Float16)v.z; bh.h[3] = (_Float16)v.w;
            *(ushort4*)(&As[row][k4 * 4]) = bh.u;
        }
        // stage B fragments for this kb: 8 runs x 4 KB, coalesced 16B chunks
        #pragma unroll
        for (int run = 0; run < 8; ++run) {
            const int nt = (run >> 1) * 8 + bx * 2 + (run & 1);
            const uint4 v = ((const uint4*)(uh + (size_t)(nt * 32 + kb * 4) * 512))[t];
            *(uint4*)(&Bs[run * 2048 + t * 8]) = v;
        }
        __syncthreads();
        #pragma unroll
        for (int kc = 0; kc < 4; ++kc) {
            f16x8 af = *(const f16x8*)(&As[w * 32 + (lane & 31)][kc * 16 + (lane >> 5) * 8]);
            #pragma unroll
            for (int et = 0; et < 8; ++et) {
                f16x8 bh = *(const f16x8*)(&Bs[et * 2048 + kc * 512 + lane * 8]);
                acc[et] = __builtin_amdgcn_mfma_f32_32x32x16_f16(af, bh, acc[et], 0, 0, 0);
            }
        }
    }

    const int col32 = lane & 31;
    const int rbase = m0 + w * 32 + 4 * (lane >> 5);
    #pragma unroll
    for (int jh = 0; jh < 2; ++jh) {
        const int col = bx * 64 + jh * 32 + col32;
        const float bi = bias[col];
        const float bf_ = bias[256 + col];
        const float bo = bias[512 + col];
        const float bg = bias[768 + col];
        const f32x16 zi = acc[0 * 2 + jh];
        const f32x16 zf = acc[1 * 2 + jh];
        const f32x16 zo = acc[2 * 2 + jh];
        const f32x16 zg = acc[3 * 2 + jh];
        #pragma unroll
        for (int reg = 0; reg < 16; ++reg) {
            const int row = rbase + (reg & 3) + 8 * (reg >> 2);
            const size_t idx = (size_t)row * DIM + col;
            const float ig = sigmoidf_(zi[reg] + bi);
            const float fg = sigmoidf_(zf[reg] + bf_);
            const float og = sigmoidf_(zo[reg] + bo);
            const float gg = tanh_fast(zg[reg] + bg);
            const float cn = fg * c[idx] + ig * gg;
            c[idx] = cn;
            const float hn = og * tanh_fast(cn);
            h_out[idx] = hn;
            if (hdup) hdup[(size_t)row * 512 + col] = hn;
        }
    }
}

// ---------------------------------------------------------------------------
extern "C" void kernel_launch(void* const* d_in, const int* in_sizes, int n_in,
                              void* d_out, int out_size, void* d_ws, size_t ws_size,
                              hipStream_t stream) {
    const float* x     = (const float*)d_in[0];
    const int*   split = (const int*)d_in[1];
    const float* U     = (const float*)d_in[2];
    const float* bias  = (const float*)d_in[3];
    float* out = (float*)d_out;

    char* ws = (char*)d_ws;
    const size_t lb_bytes  = ((size_t)(NB + 1) * sizeof(int) + 255) & ~(size_t)255;
    const size_t mat_bytes = (size_t)NB * DIM * sizeof(float);   // 16 MB
    int*   lb   = (int*)ws;
    float* hA   = (float*)(ws + lb_bytes);
    float* hB   = (float*)(ws + lb_bytes + mat_bytes);
    float* cbuf = (float*)(ws + lb_bytes + 2 * mat_bytes);
    float* rbuf = (float*)(ws + lb_bytes + 3 * mat_bytes);
    _Float16* uh = (_Float16*)(ws + lb_bytes + 4 * mat_bytes);                 // 1 MB
    _Float16* xh = (_Float16*)(ws + lb_bytes + 4 * mat_bytes + (1 << 20));     // 256 MB

    bounds_kernel<<<(NB + 1 + 255) / 256, 256, 0, stream>>>(split, lb);
    uswz_kernel<<<1024, 256, 0, stream>>>(U, uh);
    hipMemsetAsync(cbuf, 0, mat_bytes, stream);

    float* h_cur = hA;
    float* h_nxt = hB;
    for (int m = 0; m < M_STEPS; ++m) {
        const bool last = (m == M_STEPS - 1);
        float* rdst   = last ? (out + DIM) : rbuf;
        int    rstrid = last ? (2 * DIM) : DIM;
        if (m == 0) {
            // h == 0: r = segment mean; also emits fp16 x for later passes
            attn0_cvt_kernel<<<NB / 4, 256, 0, stream>>>(x, lb, rbuf, xh);
        } else {
            attn_f16_kernel<<<NB / 4, 256, 0, stream>>>(xh, lb, h_cur, rdst, rstrid);
        }
        if (!last) {
            dim3 grid(4, NB / LBM);
            float* hdup = (m == M_STEPS - 2) ? out : (float*)nullptr;
            lstm_mfma_kernel<<<grid, 256, 0, stream>>>(
                (m == 0) ? rbuf : h_cur, rbuf, uh, bias, cbuf, h_nxt, hdup,
                (m == 0) ? 4 : 0);
            float* tmp = h_cur; h_cur = h_nxt; h_nxt = tmp;
        }
    }
}

// Round 4
// 1243.842 us; speedup vs baseline: 1.3612x; 1.0254x over previous
//
#include <hip/hip_runtime.h>
#include <hip/hip_bf16.h>
#include <math.h>

#define N_ATOMS 524288
#define DIM 256
#define NB 16384          // number of molecules / segments
#define M_STEPS 6

#define SEG 64            // segments per block
#define NTHREADS 512      // 8 waves
#define SEGW 8            // segments per wave
#define AST 520           // A row stride (fp16): 512 cols + 8 pad (4-way-max LDS banks)

typedef _Float16 f16x8 __attribute__((ext_vector_type(8)));
typedef float f32x16 __attribute__((ext_vector_type(16)));

__device__ __forceinline__ float sigmoidf_(float z) {
    return 1.0f / (1.0f + __expf(-z));
}
__device__ __forceinline__ float tanh_fast(float z) {
    return 1.0f - 2.0f / (__expf(2.0f * z) + 1.0f);
}
// unpack a uint holding two fp16
__device__ __forceinline__ float2 h2f2(unsigned u) {
    union { unsigned u; _Float16 h[2]; } x; x.u = u;
    float2 r; r.x = (float)x.h[0]; r.y = (float)x.h[1]; return r;
}

// ---------------------------------------------------------------------------
// Kernel 1: segment bounds via binary search (atom_split is sorted)
// ---------------------------------------------------------------------------
__global__ void bounds_kernel(const int* __restrict__ split, int* __restrict__ lb) {
    int b = blockIdx.x * blockDim.x + threadIdx.x;
    if (b > NB) return;
    int lo = 0, hi = N_ATOMS;
    while (lo < hi) {
        int mid = (lo + hi) >> 1;
        if (split[mid] < b) lo = mid + 1; else hi = mid;
    }
    lb[b] = lo;
}

// ---------------------------------------------------------------------------
// Kernel 2: pre-swizzle U (f32 [512,1024]) into fp16 B-fragment order for
// mfma_f32_32x32x16_f16. Frag f = nt*32 + kc; lane l holds
// B[k = kc*16 + (l>>5)*8 + jj][n = nt*32 + (l&31)], jj=0..7. 1 MB total.
// ---------------------------------------------------------------------------
__global__ __launch_bounds__(256) void uswz_kernel(const float* __restrict__ U,
                                                   _Float16* __restrict__ uh) {
    int d = blockIdx.x * 256 + threadIdx.x;
    int f = d >> 8;
    int r = d & 255;
    int jjp = r >> 6;
    int lane = r & 63;
    int nt = f >> 5, kc = f & 31;
    int n = nt * 32 + (lane & 31);
    int k = kc * 16 + (lane >> 5) * 8 + jjp * 2;
    union { unsigned u; _Float16 h[2]; } p;
    p.h[0] = (_Float16)U[(size_t)k * 1024 + n];
    p.h[1] = (_Float16)U[(size_t)(k + 1) * 1024 + n];
    *(unsigned*)(&uh[(size_t)(f * 64 + lane) * 8 + jjp * 2]) = p.u;
}

// ---------------------------------------------------------------------------
// Kernel 3: FULLY FUSED Set2Set. The recurrence is segment-local, so one
// block owns 64 segments and runs all 6 steps internally:
//   phase0: mean-attn over fp32 x (h=0 -> uniform softmax), emit fp16 x copy
//   5x { GEMM [h|r]@U via MFMA from LDS-A -> gates -> h,c ; attn over fp16 x }
// h lives in A[.][0:256) fp16, r in A[.][256:512) fp16, c in LDS fp32.
// No h/r/c global round trips, 3 kernel launches total, no memsets.
// ---------------------------------------------------------------------------
__global__ __launch_bounds__(NTHREADS, 1) void set2set_fused_kernel(
    const float* __restrict__ x,       // [N_ATOMS, DIM] fp32
    const int* __restrict__ lb,        // [NB+1]
    const _Float16* __restrict__ uh,   // pre-swizzled U fp16 fragments
    const float* __restrict__ bias,    // [1024]
    _Float16* __restrict__ xh,         // [N_ATOMS, DIM] fp16 scratch
    float* __restrict__ out)           // [NB, 512]
{
    extern __shared__ char smem[];
    _Float16 (*A)[AST]  = (_Float16(*)[AST])smem;                       // 66560 B
    float    (*Cs)[DIM] = (float(*)[DIM])(smem + SEG * AST * 2);        // 65536 B
    int*     lbs        = (int*)(smem + SEG * AST * 2 + SEG * DIM * 4); // 260 B

    const int t    = threadIdx.x;
    const int w    = t >> 6;
    const int lane = t & 63;
    const int g    = lane >> 4;       // atom subgroup 0..3
    const int q    = lane & 15;       // dim subgroup 0..15
    const int s0seg = blockIdx.x * SEG;

    if (t <= SEG) lbs[t] = lb[s0seg + t];
    // zero h-half of A and c
    for (int idx = t; idx < SEG * 64; idx += NTHREADS) {
        int row = idx >> 6, j4 = idx & 63;
        uint2 z; z.x = 0u; z.y = 0u;
        *(uint2*)(&A[row][j4 * 4]) = z;                 // cols 0..255 (h) = 0
        float4 zf = {0.f, 0.f, 0.f, 0.f};
        *(float4*)(&Cs[row][j4 * 4]) = zf;
    }
    // hoist bias (constant across steps); wave w owns gate-cols d in [w*32, w*32+32)
    const int col32 = lane & 31;
    const int d     = w * 32 + col32;
    const float bi  = bias[d];
    const float bf_ = bias[256 + d];
    const float bo  = bias[512 + d];
    const float bg  = bias[768 + d];
    __syncthreads();

#define XRED(v) { v += __shfl_xor(v, 16, 64); v += __shfl_xor(v, 32, 64); }

    // ---------------- phase 0: mean + fp16 conversion ----------------
    for (int js = 0; js < SEGW; ++js) {
        const int sl = w * SEGW + js;
        const int s = lbs[sl], e = lbs[sl + 1];
        float a0x=0.f,a0y=0.f,a0z=0.f,a0w=0.f;
        float a1x=0.f,a1y=0.f,a1z=0.f,a1w=0.f;
        float a2x=0.f,a2y=0.f,a2z=0.f,a2w=0.f;
        float a3x=0.f,a3y=0.f,a3z=0.f,a3w=0.f;
        float cnt = 0.f;
        int i = s + g;
        float4 c0={0,0,0,0}, c1={0,0,0,0}, c2={0,0,0,0}, c3={0,0,0,0};
        if (i < e) {
            const float* xr = &x[(size_t)i * DIM + q * 16];
            c0 = *(const float4*)(xr + 0);  c1 = *(const float4*)(xr + 4);
            c2 = *(const float4*)(xr + 8);  c3 = *(const float4*)(xr + 12);
        }
        while (i < e) {
            const int inext = i + 4;
            const int iload = (inext < e) ? inext : i;
            const float* xr = &x[(size_t)iload * DIM + q * 16];
            const float4 n0 = *(const float4*)(xr + 0);
            const float4 n1 = *(const float4*)(xr + 4);
            const float4 n2 = *(const float4*)(xr + 8);
            const float4 n3 = *(const float4*)(xr + 12);

            union { _Float16 h[16]; uint4 v[2]; } P;
            P.h[0]=(_Float16)c0.x; P.h[1]=(_Float16)c0.y; P.h[2]=(_Float16)c0.z; P.h[3]=(_Float16)c0.w;
            P.h[4]=(_Float16)c1.x; P.h[5]=(_Float16)c1.y; P.h[6]=(_Float16)c1.z; P.h[7]=(_Float16)c1.w;
            P.h[8]=(_Float16)c2.x; P.h[9]=(_Float16)c2.y; P.h[10]=(_Float16)c2.z; P.h[11]=(_Float16)c2.w;
            P.h[12]=(_Float16)c3.x; P.h[13]=(_Float16)c3.y; P.h[14]=(_Float16)c3.z; P.h[15]=(_Float16)c3.w;
            uint4* xw = (uint4*)(&xh[(size_t)i * DIM + q * 16]);
            xw[0] = P.v[0]; xw[1] = P.v[1];

            cnt += 1.f;
            a0x += c0.x; a0y += c0.y; a0z += c0.z; a0w += c0.w;
            a1x += c1.x; a1y += c1.y; a1z += c1.z; a1w += c1.w;
            a2x += c2.x; a2y += c2.y; a2z += c2.z; a2w += c2.w;
            a3x += c3.x; a3y += c3.y; a3z += c3.z; a3w += c3.w;
            c0=n0; c1=n1; c2=n2; c3=n3;
            i = inext;
        }
        XRED(a0x) XRED(a0y) XRED(a0z) XRED(a0w)
        XRED(a1x) XRED(a1y) XRED(a1z) XRED(a1w)
        XRED(a2x) XRED(a2y) XRED(a2z) XRED(a2w)
        XRED(a3x) XRED(a3y) XRED(a3z) XRED(a3w)
        XRED(cnt)
        const float inv = (cnt > 0.f) ? (1.0f / cnt) : 0.f;
        float vx = (g==0) ? a0x : (g==1) ? a1x : (g==2) ? a2x : a3x;
        float vy = (g==0) ? a0y : (g==1) ? a1y : (g==2) ? a2y : a3y;
        float vz = (g==0) ? a0z : (g==1) ? a1z : (g==2) ? a2z : a3z;
        float vw = (g==0) ? a0w : (g==1) ? a1w : (g==2) ? a2w : a3w;
        union { _Float16 h[4]; uint2 u; } R;
        R.h[0]=(_Float16)(vx*inv); R.h[1]=(_Float16)(vy*inv);
        R.h[2]=(_Float16)(vz*inv); R.h[3]=(_Float16)(vw*inv);
        *(uint2*)(&A[sl][256 + q * 16 + g * 4]) = R.u;
    }
    __syncthreads();

    // ---------------- 5 x (LSTM step + attention pass) ----------------
    for (int m = 0; m < M_STEPS - 1; ++m) {
        // ---- GEMM: z = [h|r] @ U.  A is already fp16 in LDS. ----
        f32x16 acc[8];
        #pragma unroll
        for (int et = 0; et < 8; ++et)
            #pragma unroll
            for (int qq = 0; qq < 16; ++qq) acc[et][qq] = 0.0f;

        #pragma unroll 4
        for (int kc = 0; kc < 32; ++kc) {
            const int kof = kc * 16 + (lane >> 5) * 8;
            f16x8 af0 = *(const f16x8*)(&A[(lane & 31)][kof]);
            f16x8 af1 = *(const f16x8*)(&A[32 + (lane & 31)][kof]);
            #pragma unroll
            for (int gate = 0; gate < 4; ++gate) {
                const int nt = gate * 8 + w;
                f16x8 bfr = *(const f16x8*)(&uh[(size_t)(nt * 32 + kc) * 512 + lane * 8]);
                acc[gate * 2 + 0] = __builtin_amdgcn_mfma_f32_32x32x16_f16(af0, bfr, acc[gate * 2 + 0], 0, 0, 0);
                acc[gate * 2 + 1] = __builtin_amdgcn_mfma_f32_32x32x16_f16(af1, bfr, acc[gate * 2 + 1], 0, 0, 0);
            }
        }
        __syncthreads();   // all MFMA A-reads done before epilogue writes A

        // ---- epilogue: gates -> c (LDS fp32), h -> A fp16 (+ out at m==4) ----
        #pragma unroll
        for (int mt = 0; mt < 2; ++mt) {
            const int rb = mt * 32 + 4 * (lane >> 5);
            #pragma unroll
            for (int reg = 0; reg < 16; ++reg) {
                const int row = rb + (reg & 3) + 8 * (reg >> 2);
                const float ig = sigmoidf_(acc[0 + mt][reg] + bi);
                const float fg = sigmoidf_(acc[2 + mt][reg] + bf_);
                const float og = sigmoidf_(acc[4 + mt][reg] + bo);
                const float gg = tanh_fast(acc[6 + mt][reg] + bg);
                const float cn = fg * Cs[row][d] + ig * gg;
                Cs[row][d] = cn;
                const float hn = og * tanh_fast(cn);
                A[row][d] = (_Float16)hn;
                if (m == M_STEPS - 2)
                    out[(size_t)(s0seg + row) * 512 + d] = hn;
            }
        }
        __syncthreads();   // h visible to attention

        // ---- attention pass m+1 over fp16 x, h from A ----
        const bool last = (m == M_STEPS - 2);
        for (int js = 0; js < SEGW; ++js) {
            const int sl = w * SEGW + js;
            const int s = lbs[sl], e = lbs[sl + 1];

            const uint4* hr = (const uint4*)(&A[sl][q * 16]);
            const uint4 H0 = hr[0], H1 = hr[1];
            const float2 h0 = h2f2(H0.x), h1 = h2f2(H0.y), h2_ = h2f2(H0.z), h3 = h2f2(H0.w);
            const float2 h4 = h2f2(H1.x), h5 = h2f2(H1.y), h6 = h2f2(H1.z), h7 = h2f2(H1.w);
            const float4 hv0 = {h0.x, h0.y, h1.x, h1.y};
            const float4 hv1 = {h2_.x, h2_.y, h3.x, h3.y};
            const float4 hv2 = {h4.x, h4.y, h5.x, h5.y};
            const float4 hv3 = {h6.x, h6.y, h7.x, h7.y};

            float a0x=0.f,a0y=0.f,a0z=0.f,a0w=0.f;
            float a1x=0.f,a1y=0.f,a1z=0.f,a1w=0.f;
            float a2x=0.f,a2y=0.f,a2z=0.f,a2w=0.f;
            float a3x=0.f,a3y=0.f,a3z=0.f,a3w=0.f;
            float ssum = 0.f;

            int i = s + g;
            uint4 Au = {0,0,0,0}, Bu = {0,0,0,0};
            if (i < e) {
                const uint4* xr = (const uint4*)(&xh[(size_t)i * DIM + q * 16]);
                Au = xr[0]; Bu = xr[1];
            }
            while (i < e) {
                const int inext = i + 4;
                const int iload = (inext < e) ? inext : i;
                const uint4* xr = (const uint4*)(&xh[(size_t)iload * DIM + q * 16]);
                const uint4 nA = xr[0];
                const uint4 nB = xr[1];

                const float2 p0 = h2f2(Au.x), p1 = h2f2(Au.y), p2 = h2f2(Au.z), p3 = h2f2(Au.w);
                const float2 p4 = h2f2(Bu.x), p5 = h2f2(Bu.y), p6 = h2f2(Bu.z), p7 = h2f2(Bu.w);
                const float4 c0 = {p0.x, p0.y, p1.x, p1.y};
                const float4 c1 = {p2.x, p2.y, p3.x, p3.y};
                const float4 c2 = {p4.x, p4.y, p5.x, p5.y};
                const float4 c3 = {p6.x, p6.y, p7.x, p7.y};

                float d01 = c0.x*hv0.x + c0.y*hv0.y + c0.z*hv0.z + c0.w*hv0.w
                          + c1.x*hv1.x + c1.y*hv1.y + c1.z*hv1.z + c1.w*hv1.w;
                float d23 = c2.x*hv2.x + c2.y*hv2.y + c2.z*hv2.z + c2.w*hv2.w
                          + c3.x*hv3.x + c3.y*hv3.y + c3.z*hv3.z + c3.w*hv3.w;
                float dd = d01 + d23;
                dd += __shfl_xor(dd, 1, 64);
                dd += __shfl_xor(dd, 2, 64);
                dd += __shfl_xor(dd, 4, 64);
                dd += __shfl_xor(dd, 8, 64);
                const float ee = __expf(dd);
                ssum += ee;
                a0x += ee*c0.x; a0y += ee*c0.y; a0z += ee*c0.z; a0w += ee*c0.w;
                a1x += ee*c1.x; a1y += ee*c1.y; a1z += ee*c1.z; a1w += ee*c1.w;
                a2x += ee*c2.x; a2y += ee*c2.y; a2z += ee*c2.z; a2w += ee*c2.w;
                a3x += ee*c3.x; a3y += ee*c3.y; a3z += ee*c3.z; a3w += ee*c3.w;

                Au = nA; Bu = nB;
                i = inext;
            }
            XRED(a0x) XRED(a0y) XRED(a0z) XRED(a0w)
            XRED(a1x) XRED(a1y) XRED(a1z) XRED(a1w)
            XRED(a2x) XRED(a2y) XRED(a2z) XRED(a2w)
            XRED(a3x) XRED(a3y) XRED(a3z) XRED(a3w)
            XRED(ssum)
            const float inv = (ssum > 0.f) ? (1.0f / ssum) : 0.f;
            float vx = (g==0) ? a0x : (g==1) ? a1x : (g==2) ? a2x : a3x;
            float vy = (g==0) ? a0y : (g==1) ? a1y : (g==2) ? a2y : a3y;
            float vz = (g==0) ? a0z : (g==1) ? a1z : (g==2) ? a2z : a3z;
            float vw = (g==0) ? a0w : (g==1) ? a1w : (g==2) ? a2w : a3w;
            if (last) {
                float4 v; v.x = vx*inv; v.y = vy*inv; v.z = vz*inv; v.w = vw*inv;
                *(float4*)(&out[(size_t)(s0seg + sl) * 512 + 256 + q * 16 + g * 4]) = v;
            } else {
                union { _Float16 h[4]; uint2 u; } R;
                R.h[0]=(_Float16)(vx*inv); R.h[1]=(_Float16)(vy*inv);
                R.h[2]=(_Float16)(vz*inv); R.h[3]=(_Float16)(vw*inv);
                *(uint2*)(&A[sl][256 + q * 16 + g * 4]) = R.u;
            }
        }
        if (m < M_STEPS - 2) __syncthreads();   // r visible to next GEMM
    }
#undef XRED
}

// ---------------------------------------------------------------------------
extern "C" void kernel_launch(void* const* d_in, const int* in_sizes, int n_in,
                              void* d_out, int out_size, void* d_ws, size_t ws_size,
                              hipStream_t stream) {
    const float* x     = (const float*)d_in[0];
    const int*   split = (const int*)d_in[1];
    const float* U     = (const float*)d_in[2];
    const float* bias  = (const float*)d_in[3];
    float* out = (float*)d_out;

    char* ws = (char*)d_ws;
    const size_t lb_bytes = ((size_t)(NB + 1) * sizeof(int) + 255) & ~(size_t)255;
    int*      lb = (int*)ws;
    _Float16* uh = (_Float16*)(ws + lb_bytes);                 // 1 MB
    _Float16* xh = (_Float16*)(ws + lb_bytes + (1 << 20));     // 256 MB

    bounds_kernel<<<(NB + 1 + 255) / 256, 256, 0, stream>>>(split, lb);
    uswz_kernel<<<1024, 256, 0, stream>>>(U, uh);

    const int smem_bytes = SEG * AST * 2 + SEG * DIM * 4 + (SEG + 1) * 4; // 132356
    set2set_fused_kernel<<<NB / SEG, NTHREADS, smem_bytes, stream>>>(
        x, lb, uh, bias, xh, out);
}